// Round 1
// baseline (322.814 us; speedup 1.0000x reference)
//
#include <hip/hip_runtime.h>
#include <hip/hip_bf16.h>

typedef __attribute__((ext_vector_type(8))) short bf16x8;
typedef __attribute__((ext_vector_type(4))) float f32x4;

#define MFMA16(a, b, c) __builtin_amdgcn_mfma_f32_16x16x32_bf16(a, b, c, 0, 0, 0)

__device__ inline ushort f2b(float f) {
  union { float f; unsigned u; } v; v.f = f;
  unsigned u = v.u;
  u += 0x7fffu + ((u >> 16) & 1u);   // round-to-nearest-even
  return (ushort)(u >> 16);
}

// ---------------- cast f32 -> bf16 (raw ushort bits) ----------------
__global__ void cast_k(const float* __restrict__ in, ushort* __restrict__ out, int n) {
  int i = (blockIdx.x * blockDim.x + threadIdx.x) * 4;
  const int stride = gridDim.x * blockDim.x * 4;
  for (; i < n; i += stride) {
    float4 v = *reinterpret_cast<const float4*>(in + i);
    ushort4 o;
    o.x = f2b(v.x); o.y = f2b(v.y); o.z = f2b(v.z); o.w = f2b(v.w);
    *reinterpret_cast<ushort4*>(out + i) = o;
  }
}

// ---------------- GEMM: C[M,N] = A[M,K] @ B[N,K]^T (+bias) ----------------
// MODE 0: write f32 to outF (stride N) + b0[col]
// MODE 1: QKV scatter: col -> (which, h, dk); Q,K as [B,H,T,64] bf16, V^T as [B,H,64,T] bf16
template <int MODE>
__global__ __launch_bounds__(256, 2)
void gemm_bt(const ushort* __restrict__ A, const ushort* __restrict__ B,
             const float* __restrict__ b0, const float* __restrict__ b1,
             const float* __restrict__ b2,
             float* __restrict__ outF, ushort* __restrict__ Qg,
             ushort* __restrict__ Kg, ushort* __restrict__ VTg, int N) {
  __shared__ __align__(16) ushort As[128][40];
  __shared__ __align__(16) ushort Bs[128][40];
  const int tid = threadIdx.x;
  const int m0 = blockIdx.y * 128, n0 = blockIdx.x * 128;
  const int wid = tid >> 6, lane = tid & 63, g = lane >> 4, li = lane & 15;
  const int wr = (wid >> 1) * 64, wc = (wid & 1) * 64;
  f32x4 acc[4][4] = {};
  for (int k0 = 0; k0 < 1024; k0 += 32) {
#pragma unroll
    for (int it = 0; it < 2; ++it) {
      int idx = tid + it * 256;
      int row = idx >> 2, seg = idx & 3;
      *reinterpret_cast<float4*>(&As[row][seg * 8]) =
          *reinterpret_cast<const float4*>(A + (size_t)(m0 + row) * 1024 + k0 + seg * 8);
      *reinterpret_cast<float4*>(&Bs[row][seg * 8]) =
          *reinterpret_cast<const float4*>(B + (size_t)(n0 + row) * 1024 + k0 + seg * 8);
    }
    __syncthreads();
    bf16x8 af[4], bfm[4];
#pragma unroll
    for (int i = 0; i < 4; ++i) {
      af[i]  = *reinterpret_cast<const bf16x8*>(&As[wr + i * 16 + li][g * 8]);
      bfm[i] = *reinterpret_cast<const bf16x8*>(&Bs[wc + i * 16 + li][g * 8]);
    }
#pragma unroll
    for (int mi = 0; mi < 4; ++mi)
#pragma unroll
      for (int ni = 0; ni < 4; ++ni)
        acc[mi][ni] = MFMA16(af[mi], bfm[ni], acc[mi][ni]);
    __syncthreads();
  }
#pragma unroll
  for (int mi = 0; mi < 4; ++mi) {
#pragma unroll
    for (int ni = 0; ni < 4; ++ni) {
      const int col = n0 + wc + ni * 16 + li;
#pragma unroll
      for (int r = 0; r < 4; ++r) {
        const int row = m0 + wr + mi * 16 + 4 * g + r;
        float v = acc[mi][ni][r];
        if (MODE == 0) {
          outF[(size_t)row * N + col] = v + b0[col];
        } else {
          const int which = col >> 10, c = col & 1023;
          const int hh = c >> 6, dk = c & 63;
          const int bb = row >> 11, t = row & 2047;
          const float* bias = (which == 0) ? b0 : ((which == 1) ? b1 : b2);
          const ushort bv = f2b(v + bias[c]);
          const size_t bhi = (size_t)(bb * 16 + hh);
          if (which == 0)      Qg[(bhi * 2048 + t) * 64 + dk] = bv;
          else if (which == 1) Kg[(bhi * 2048 + t) * 64 + dk] = bv;
          else                 VTg[(bhi * 64 + dk) * 2048 + t] = bv;
        }
      }
    }
  }
}

// ---------------- flash attention with rel-pos bias + causal mask ----------------
// grid: (T/64, B*H), 256 threads = 4 waves, wave w owns q rows [q0+16w, q0+16w+16)
__global__ __launch_bounds__(256, 2)
void attn_k(const ushort* __restrict__ Qg, const ushort* __restrict__ Kg,
            const ushort* __restrict__ VTg, const float* __restrict__ relT,
            ushort* __restrict__ Oa) {
  __shared__ float relv[2048];
  __shared__ __align__(16) ushort Pbuf[4][16][72];
  const int q0 = blockIdx.x * 64;
  const int bh = blockIdx.y;
  const int h = bh & 15, bb = bh >> 4;
  for (int i = threadIdx.x; i < 2048; i += 256)
    relv[i] = relT[(size_t)(i + 2047) * 16 + h];
  __syncthreads();
  const int wid = threadIdx.x >> 6, lane = threadIdx.x & 63;
  const int g = lane >> 4, li = lane & 15;
  const int qb = q0 + wid * 16;
  const ushort* Qb = Qg + (size_t)bh * 2048 * 64;
  const ushort* Kb = Kg + (size_t)bh * 2048 * 64;
  const ushort* Vb = VTg + (size_t)bh * 64 * 2048;
  const bf16x8 aq0 = *reinterpret_cast<const bf16x8*>(Qb + (qb + li) * 64 + g * 8);
  const bf16x8 aq1 = *reinterpret_cast<const bf16x8*>(Qb + (qb + li) * 64 + 32 + g * 8);
  float mrow[4], lrow[4];
  f32x4 Oacc[4] = {};
#pragma unroll
  for (int r = 0; r < 4; ++r) { mrow[r] = -1e30f; lrow[r] = 0.f; }
  const int nkt = q0 / 64 + 1;
  for (int kt = 0; kt < nkt; ++kt) {
    const int kb = kt * 64;
    f32x4 s[4] = {};
#pragma unroll
    for (int c = 0; c < 4; ++c) {
      bf16x8 bk0 = *reinterpret_cast<const bf16x8*>(Kb + (kb + c * 16 + li) * 64 + g * 8);
      bf16x8 bk1 = *reinterpret_cast<const bf16x8*>(Kb + (kb + c * 16 + li) * 64 + 32 + g * 8);
      s[c] = MFMA16(aq0, bk0, s[c]);
      s[c] = MFMA16(aq1, bk1, s[c]);
    }
    float rm[4] = {-3e38f, -3e38f, -3e38f, -3e38f};
#pragma unroll
    for (int c = 0; c < 4; ++c)
#pragma unroll
      for (int r = 0; r < 4; ++r) {
        const int qrow = qb + 4 * g + r;
        const int kcol = kb + c * 16 + li;
        const int d = qrow - kcol;
        const float sv = (d >= 0) ? (s[c][r] * 0.125f + relv[d]) : -1e30f;
        s[c][r] = sv;
        rm[r] = fmaxf(rm[r], sv);
      }
#pragma unroll
    for (int off = 1; off < 16; off <<= 1)
#pragma unroll
      for (int r = 0; r < 4; ++r)
        rm[r] = fmaxf(rm[r], __shfl_xor(rm[r], off));
    float fr[4], psum[4];
#pragma unroll
    for (int r = 0; r < 4; ++r) {
      const float mn = fmaxf(mrow[r], rm[r]);
      fr[r] = __expf(mrow[r] - mn);
      mrow[r] = mn;
      psum[r] = 0.f;
    }
#pragma unroll
    for (int c = 0; c < 4; ++c)
#pragma unroll
      for (int r = 0; r < 4; ++r) {
        const float p = __expf(s[c][r] - mrow[r]);
        s[c][r] = p;
        psum[r] += p;
      }
#pragma unroll
    for (int off = 1; off < 16; off <<= 1)
#pragma unroll
      for (int r = 0; r < 4; ++r)
        psum[r] += __shfl_xor(psum[r], off);
#pragma unroll
    for (int r = 0; r < 4; ++r)
      lrow[r] = lrow[r] * fr[r] + psum[r];
#pragma unroll
    for (int c = 0; c < 4; ++c)
#pragma unroll
      for (int r = 0; r < 4; ++r)
        Oacc[c][r] *= fr[r];
    // previous iteration's P reads must drain before overwrite (wave-synchronous)
    asm volatile("s_waitcnt lgkmcnt(0)" ::: "memory");
#pragma unroll
    for (int c = 0; c < 4; ++c)
#pragma unroll
      for (int r = 0; r < 4; ++r)
        Pbuf[wid][4 * g + r][c * 16 + li] = f2b(s[c][r]);
    asm volatile("s_waitcnt lgkmcnt(0)" ::: "memory");
    const bf16x8 pa0 = *reinterpret_cast<const bf16x8*>(&Pbuf[wid][li][g * 8]);
    const bf16x8 pa1 = *reinterpret_cast<const bf16x8*>(&Pbuf[wid][li][32 + g * 8]);
#pragma unroll
    for (int c = 0; c < 4; ++c) {
      bf16x8 bv0 = *reinterpret_cast<const bf16x8*>(Vb + (size_t)(c * 16 + li) * 2048 + kb + g * 8);
      bf16x8 bv1 = *reinterpret_cast<const bf16x8*>(Vb + (size_t)(c * 16 + li) * 2048 + kb + 32 + g * 8);
      Oacc[c] = MFMA16(pa0, bv0, Oacc[c]);
      Oacc[c] = MFMA16(pa1, bv1, Oacc[c]);
    }
  }
#pragma unroll
  for (int c = 0; c < 4; ++c)
#pragma unroll
    for (int r = 0; r < 4; ++r) {
      const int qrow = qb + 4 * g + r;
      const int dk = c * 16 + li;
      const float v = Oacc[c][r] / lrow[r];
      Oa[((size_t)(bb * 2048 + qrow)) * 1024 + h * 64 + dk] = f2b(v);
    }
}

extern "C" void kernel_launch(void* const* d_in, const int* in_sizes, int n_in,
                              void* d_out, int out_size, void* d_ws, size_t ws_size,
                              hipStream_t stream) {
  const float* x    = (const float*)d_in[0];
  const float* WQ   = (const float*)d_in[1];
  const float* bQ   = (const float*)d_in[2];
  const float* WK   = (const float*)d_in[3];
  const float* bK   = (const float*)d_in[4];
  const float* WV   = (const float*)d_in[5];
  const float* bV   = (const float*)d_in[6];
  const float* WO   = (const float*)d_in[7];
  const float* bO   = (const float*)d_in[8];
  const float* relT = (const float*)d_in[9];
  float* out = (float*)d_out;

  if (ws_size < (size_t)48 * 1024 * 1024) return;  // need 48 MB scratch

  char* ws = (char*)d_ws;
  ushort* xb   = (ushort*)(ws);                            // [4096][1024] bf16
  ushort* Wcat = (ushort*)(ws + 8 * 1024 * 1024);          // [3072][1024] bf16 (WQ|WK|WV)
  ushort* WOb  = (ushort*)(ws + 14 * 1024 * 1024);         // [1024][1024] bf16
  ushort* Qg   = (ushort*)(ws + 16 * 1024 * 1024);         // [2,16,2048,64] bf16
  ushort* Kg   = (ushort*)(ws + 24 * 1024 * 1024);         // [2,16,2048,64] bf16
  ushort* VTg  = (ushort*)(ws + 32 * 1024 * 1024);         // [2,16,64,2048] bf16
  ushort* Oa   = (ushort*)(ws + 40 * 1024 * 1024);         // [4096][1024] bf16

  cast_k<<<1024, 256, 0, stream>>>(x, xb, 4096 * 1024);
  cast_k<<<512, 256, 0, stream>>>(WQ, Wcat, 1024 * 1024);
  cast_k<<<512, 256, 0, stream>>>(WK, Wcat + 1024 * 1024, 1024 * 1024);
  cast_k<<<512, 256, 0, stream>>>(WV, Wcat + 2 * 1024 * 1024, 1024 * 1024);
  cast_k<<<512, 256, 0, stream>>>(WO, WOb, 1024 * 1024);

  gemm_bt<1><<<dim3(24, 32), 256, 0, stream>>>(xb, Wcat, bQ, bK, bV,
                                               nullptr, Qg, Kg, VTg, 3072);
  attn_k<<<dim3(32, 32), 256, 0, stream>>>(Qg, Kg, VTg, relT, Oa);
  gemm_bt<0><<<dim3(8, 32), 256, 0, stream>>>(Oa, WOb, bO, nullptr, nullptr,
                                              out, nullptr, nullptr, nullptr, 1024);
}

// Round 2
// 180.629 us; speedup vs baseline: 1.7872x; 1.7872x over previous
//
#include <hip/hip_runtime.h>
#include <hip/hip_bf16.h>

typedef __attribute__((ext_vector_type(8))) short bf16x8;
typedef __attribute__((ext_vector_type(4))) float f32x4;
typedef __attribute__((ext_vector_type(16))) float f32x16;

#define MFMA16(a, b, c) __builtin_amdgcn_mfma_f32_16x16x32_bf16(a, b, c, 0, 0, 0)
#define MFMA32(a, b, c) __builtin_amdgcn_mfma_f32_32x32x16_bf16(a, b, c, 0, 0, 0)

__device__ inline ushort f2b(float f) {
  union { float f; unsigned u; } v; v.f = f;
  unsigned u = v.u;
  u += 0x7fffu + ((u >> 16) & 1u);   // round-to-nearest-even
  return (ushort)(u >> 16);
}

__device__ inline unsigned cvtpk(float lo, float hi) {
  unsigned r;
  asm("v_cvt_pk_bf16_f32 %0, %1, %2" : "=v"(r) : "v"(lo), "v"(hi));
  return r;
}

// ---------------- cast f32 -> bf16 ----------------
__global__ void cast_k(const float* __restrict__ in, ushort* __restrict__ out, int n) {
  int i = (blockIdx.x * blockDim.x + threadIdx.x) * 4;
  const int stride = gridDim.x * blockDim.x * 4;
  for (; i < n; i += stride) {
    float4 v = *reinterpret_cast<const float4*>(in + i);
    ushort4 o;
    o.x = f2b(v.x); o.y = f2b(v.y); o.z = f2b(v.z); o.w = f2b(v.w);
    *reinterpret_cast<ushort4*>(out + i) = o;
  }
}

// all 4 weight matrices in one launch: WQ|WK|WV -> wcat, WO -> wob
__global__ void cast_w(const float* __restrict__ wq, const float* __restrict__ wk,
                       const float* __restrict__ wv, const float* __restrict__ wo,
                       ushort* __restrict__ wcat, ushort* __restrict__ wob) {
  const int i = (blockIdx.x * 256 + threadIdx.x) * 4;
  const int which = i >> 20, off = i & 1048575;
  const float* src = (which == 0) ? wq : (which == 1) ? wk : (which == 2) ? wv : wo;
  float4 v = *reinterpret_cast<const float4*>(src + off);
  ushort4 o;
  o.x = f2b(v.x); o.y = f2b(v.y); o.z = f2b(v.z); o.w = f2b(v.w);
  if (which < 3) *reinterpret_cast<ushort4*>(wcat + i) = o;
  else           *reinterpret_cast<ushort4*>(wob + off) = o;
}

// ---------------- GEMM: C[M,N] = A[M,K] @ B[N,K]^T (+bias), global_load_lds staging ----
template <int MODE>
__global__ __launch_bounds__(256, 2)
void gemm_bt(const ushort* __restrict__ A, const ushort* __restrict__ B,
             const float* __restrict__ b0, const float* __restrict__ b1,
             const float* __restrict__ b2,
             float* __restrict__ outF, ushort* __restrict__ Qg,
             ushort* __restrict__ Kg, ushort* __restrict__ VTg, int N) {
  __shared__ __align__(16) ushort As[128][32];
  __shared__ __align__(16) ushort Bs[128][32];
  const int tid = threadIdx.x;
  const int m0 = blockIdx.y * 128, n0 = blockIdx.x * 128;
  const int wid = tid >> 6, lane = tid & 63, g = lane >> 4, li = lane & 15;
  const int wr = (wid >> 1) * 64, wc = (wid & 1) * 64;
  const int srow = lane >> 2, scol = (lane & 3) * 8;
  const ushort* gA0 = A + (size_t)(m0 + wid * 32 + srow) * 1024 + scol;
  const ushort* gB0 = B + (size_t)(n0 + wid * 32 + srow) * 1024 + scol;
  ushort* lA0 = &As[wid * 32][0];
  ushort* lA1 = &As[wid * 32 + 16][0];
  ushort* lB0 = &Bs[wid * 32][0];
  ushort* lB1 = &Bs[wid * 32 + 16][0];
  f32x4 acc[4][4] = {};
  for (int k0 = 0; k0 < 1024; k0 += 32) {
    __builtin_amdgcn_global_load_lds((const __attribute__((address_space(1))) void*)(gA0 + k0),
                                     (__attribute__((address_space(3))) void*)lA0, 16, 0, 0);
    __builtin_amdgcn_global_load_lds((const __attribute__((address_space(1))) void*)(gA0 + 16 * 1024 + k0),
                                     (__attribute__((address_space(3))) void*)lA1, 16, 0, 0);
    __builtin_amdgcn_global_load_lds((const __attribute__((address_space(1))) void*)(gB0 + k0),
                                     (__attribute__((address_space(3))) void*)lB0, 16, 0, 0);
    __builtin_amdgcn_global_load_lds((const __attribute__((address_space(1))) void*)(gB0 + 16 * 1024 + k0),
                                     (__attribute__((address_space(3))) void*)lB1, 16, 0, 0);
    __syncthreads();
    bf16x8 af[4], bfm[4];
#pragma unroll
    for (int i = 0; i < 4; ++i) {
      af[i]  = *reinterpret_cast<const bf16x8*>(&As[wr + i * 16 + li][g * 8]);
      bfm[i] = *reinterpret_cast<const bf16x8*>(&Bs[wc + i * 16 + li][g * 8]);
    }
#pragma unroll
    for (int mi = 0; mi < 4; ++mi)
#pragma unroll
      for (int ni = 0; ni < 4; ++ni)
        acc[mi][ni] = MFMA16(af[mi], bfm[ni], acc[mi][ni]);
    __syncthreads();
  }
#pragma unroll
  for (int mi = 0; mi < 4; ++mi) {
#pragma unroll
    for (int ni = 0; ni < 4; ++ni) {
      const int col = n0 + wc + ni * 16 + li;
#pragma unroll
      for (int r = 0; r < 4; ++r) {
        const int row = m0 + wr + mi * 16 + 4 * g + r;
        float v = acc[mi][ni][r];
        if (MODE == 0) {
          outF[(size_t)row * N + col] = v + b0[col];
        } else {
          const int which = col >> 10, c = col & 1023;
          const int hh = c >> 6, dk = c & 63;
          const int bb = row >> 11, t = row & 2047;
          const float* bias = (which == 0) ? b0 : ((which == 1) ? b1 : b2);
          const ushort bv = f2b(v + bias[c]);
          const size_t bhi = (size_t)(bb * 16 + hh);
          if (which == 0)      Qg[(bhi * 2048 + t) * 64 + dk] = bv;
          else if (which == 1) Kg[(bhi * 2048 + t) * 64 + dk] = bv;
          else                 VTg[(bhi * 64 + dk) * 2048 + t] = bv;
        }
      }
    }
  }
}

// ---------------- flash attention, swapped-operand 32x32 MFMA ----------------
// Each wave owns a 32-row q-tile. S^T = mfma32(K, Q): lane holds 32 k-values of
// ONE q-row (col = lane&31) -> softmax is in-lane + one shfl_xor(32).
// scores pre-scaled to exp2 domain (relv holds log2e * bias).
template <bool MASK>
__device__ __forceinline__ void attn_tile(
    int kb, int q, int li, int hi,
    const ushort* __restrict__ Kb, const ushort* __restrict__ Vb,
    const float* relv, const bf16x8* qf,
    f32x16* O, float& m, float& l) {
  f32x16 S[2];
#pragma unroll
  for (int b = 0; b < 2; ++b) {
    f32x16 s = {};
#pragma unroll
    for (int c = 0; c < 4; ++c) {
      bf16x8 kf = *reinterpret_cast<const bf16x8*>(Kb + (size_t)(kb + b * 32 + li) * 64 + c * 16 + hi * 8);
      s = MFMA32(kf, qf[c], s);
    }
    S[b] = s;
  }
  float mx = -3e38f;
#pragma unroll
  for (int b = 0; b < 2; ++b)
#pragma unroll
    for (int r = 0; r < 16; ++r) {
      const int kloc = (r & 3) + 8 * (r >> 2) + 4 * hi + 32 * b;
      const int d = q - kb - kloc;
      const int dm = MASK ? (d & 2047) : d;
      float sv = fmaf(S[b][r], 0.1803368801111244f, relv[dm]);  // 0.125*log2(e)
      if (MASK) sv = (d >= 0) ? sv : -3e38f;
      S[b][r] = sv;
      mx = fmaxf(mx, sv);
    }
  mx = fmaxf(mx, __shfl_xor(mx, 32));
  const float mnew = fmaxf(m, mx);
  const float corr = __builtin_amdgcn_exp2f(m - mnew);
  m = mnew;
  float ps = 0.f;
#pragma unroll
  for (int b = 0; b < 2; ++b)
#pragma unroll
    for (int r = 0; r < 16; ++r) {
      const float p = __builtin_amdgcn_exp2f(S[b][r] - mnew);
      S[b][r] = p;
      ps += p;
    }
  ps += __shfl_xor(ps, 32);
  l = l * corr + ps;
#pragma unroll
  for (int b = 0; b < 2; ++b)
#pragma unroll
    for (int r = 0; r < 16; ++r)
      O[b][r] *= corr;
  // pack P to bf16 quads: U[b][rg] covers k_local = 8*rg + 4*hi + {0..3}
  unsigned U[2][4][2];
#pragma unroll
  for (int b = 0; b < 2; ++b)
#pragma unroll
    for (int rg = 0; rg < 4; ++rg) {
      U[b][rg][0] = cvtpk(S[b][4 * rg + 0], S[b][4 * rg + 1]);
      U[b][rg][1] = cvtpk(S[b][4 * rg + 2], S[b][4 * rg + 3]);
    }
  // re-fragment into PV B-operand per 16-k chunk via half-wave exchange
#pragma unroll
  for (int c = 0; c < 4; ++c) {
    const int b = c >> 1, c0 = c & 1;
    const unsigned s0 = hi ? U[b][2 * c0][0] : U[b][2 * c0 + 1][0];
    const unsigned s1 = hi ? U[b][2 * c0][1] : U[b][2 * c0 + 1][1];
    const unsigned r0 = (unsigned)__shfl_xor((int)s0, 32);
    const unsigned r1 = (unsigned)__shfl_xor((int)s1, 32);
    union { unsigned u[4]; bf16x8 v; } P;
    P.u[0] = hi ? r0 : U[b][2 * c0][0];
    P.u[1] = hi ? r1 : U[b][2 * c0][1];
    P.u[2] = hi ? U[b][2 * c0 + 1][0] : r0;
    P.u[3] = hi ? U[b][2 * c0 + 1][1] : r1;
#pragma unroll
    for (int db = 0; db < 2; ++db) {
      bf16x8 vf = *reinterpret_cast<const bf16x8*>(Vb + (size_t)(db * 32 + li) * 2048 + kb + c * 16 + hi * 8);
      O[db] = MFMA32(vf, P.v, O[db]);
    }
  }
}

// grid: 512 blocks (1-D, XCD-grouped so each bh's K/V stays on one XCD's L2)
__global__ __launch_bounds__(256, 2)
void attn_k(const ushort* __restrict__ Qg, const ushort* __restrict__ Kg,
            const ushort* __restrict__ VTg, const float* __restrict__ relT,
            ushort* __restrict__ Oa) {
  __shared__ float relv[2048];
  const int f = blockIdx.x;
  const int bh = (f & 7) + 8 * (f >> 7);   // same bh -> same XCD
  const int x = (f >> 3) & 15;
  const int h = bh & 15, bb = bh >> 4;
  for (int i = threadIdx.x; i < 2048; i += 256)
    relv[i] = relT[(size_t)(i + 2047) * 16 + h] * 1.4426950408889634f;
  __syncthreads();
  const int wid = threadIdx.x >> 6, lane = threadIdx.x & 63;
  const int li = lane & 31, hi = lane >> 5;
  // complementary q-tiles -> every block has equal total work
  const int qt = (wid == 0) ? x : (wid == 1) ? (31 - x) : (wid == 2) ? (32 + x) : (63 - x);
  const int qb = qt * 32, q = qb + li;
  const ushort* Qb = Qg + (size_t)bh * 2048 * 64;
  const ushort* Kb = Kg + (size_t)bh * 2048 * 64;
  const ushort* Vb = VTg + (size_t)bh * 64 * 2048;
  bf16x8 qf[4];
#pragma unroll
  for (int c = 0; c < 4; ++c)
    qf[c] = *reinterpret_cast<const bf16x8*>(Qb + (size_t)q * 64 + c * 16 + hi * 8);
  f32x16 O[2] = {};
  float m = -3e38f, l = 0.f;
  const int nkt = qt / 2 + 1;
  for (int kt = 0; kt < nkt - 1; ++kt)
    attn_tile<false>(kt * 64, q, li, hi, Kb, Vb, relv, qf, O, m, l);
  attn_tile<true>((nkt - 1) * 64, q, li, hi, Kb, Vb, relv, qf, O, m, l);
  const float linv = 1.f / l;
  ushort* orow = Oa + ((size_t)(bb * 2048 + q)) * 1024 + h * 64;
#pragma unroll
  for (int db = 0; db < 2; ++db)
#pragma unroll
    for (int rg = 0; rg < 4; ++rg) {
      ushort4 o;
      o.x = f2b(O[db][4 * rg + 0] * linv);
      o.y = f2b(O[db][4 * rg + 1] * linv);
      o.z = f2b(O[db][4 * rg + 2] * linv);
      o.w = f2b(O[db][4 * rg + 3] * linv);
      *reinterpret_cast<ushort4*>(orow + db * 32 + 8 * rg + 4 * hi) = o;
    }
}

extern "C" void kernel_launch(void* const* d_in, const int* in_sizes, int n_in,
                              void* d_out, int out_size, void* d_ws, size_t ws_size,
                              hipStream_t stream) {
  const float* x    = (const float*)d_in[0];
  const float* WQ   = (const float*)d_in[1];
  const float* bQ   = (const float*)d_in[2];
  const float* WK   = (const float*)d_in[3];
  const float* bK   = (const float*)d_in[4];
  const float* WV   = (const float*)d_in[5];
  const float* bV   = (const float*)d_in[6];
  const float* WO   = (const float*)d_in[7];
  const float* bO   = (const float*)d_in[8];
  const float* relT = (const float*)d_in[9];
  float* out = (float*)d_out;

  if (ws_size < (size_t)48 * 1024 * 1024) return;

  char* ws = (char*)d_ws;
  ushort* xb   = (ushort*)(ws);                            // [4096][1024] bf16
  ushort* Wcat = (ushort*)(ws + 8 * 1024 * 1024);          // [3072][1024] bf16 (WQ|WK|WV)
  ushort* WOb  = (ushort*)(ws + 14 * 1024 * 1024);         // [1024][1024] bf16
  ushort* Qg   = (ushort*)(ws + 16 * 1024 * 1024);         // [2,16,2048,64] bf16
  ushort* Kg   = (ushort*)(ws + 24 * 1024 * 1024);         // [2,16,2048,64] bf16
  ushort* VTg  = (ushort*)(ws + 32 * 1024 * 1024);         // [2,16,64,2048] bf16
  ushort* Oa   = (ushort*)(ws + 40 * 1024 * 1024);         // [4096][1024] bf16

  cast_k<<<1024, 256, 0, stream>>>(x, xb, 4096 * 1024);
  cast_w<<<4096, 256, 0, stream>>>(WQ, WK, WV, WO, Wcat, WOb);

  gemm_bt<1><<<dim3(24, 32), 256, 0, stream>>>(xb, Wcat, bQ, bK, bV,
                                               nullptr, Qg, Kg, VTg, 3072);
  attn_k<<<512, 256, 0, stream>>>(Qg, Kg, VTg, relT, Oa);
  gemm_bt<0><<<dim3(8, 32), 256, 0, stream>>>(Oa, WOb, bO, nullptr, nullptr,
                                              out, nullptr, nullptr, nullptr, 1024);
}

// Round 3
// 165.449 us; speedup vs baseline: 1.9511x; 1.0917x over previous
//
#include <hip/hip_runtime.h>
#include <hip/hip_bf16.h>

typedef __attribute__((ext_vector_type(8))) short bf16x8;
typedef __attribute__((ext_vector_type(4))) float f32x4;
typedef __attribute__((ext_vector_type(16))) float f32x16;

#define MFMA16(a, b, c) __builtin_amdgcn_mfma_f32_16x16x32_bf16(a, b, c, 0, 0, 0)
#define MFMA32(a, b, c) __builtin_amdgcn_mfma_f32_32x32x16_bf16(a, b, c, 0, 0, 0)

__device__ inline ushort f2b(float f) {
  union { float f; unsigned u; } v; v.f = f;
  unsigned u = v.u;
  u += 0x7fffu + ((u >> 16) & 1u);   // round-to-nearest-even
  return (ushort)(u >> 16);
}

__device__ inline unsigned cvtpk(float lo, float hi) {
  unsigned r;
  asm("v_cvt_pk_bf16_f32 %0, %1, %2" : "=v"(r) : "v"(lo), "v"(hi));
  return r;
}

// v_permlane32_swap_b32: a.hi <-> b.lo  =>  a' = [a.lo | b.lo], b' = [a.hi | b.hi]
__device__ inline void plswap(unsigned& a, unsigned& b) {
  asm("v_permlane32_swap_b32 %0, %1" : "+v"(a), "+v"(b));
}

// ---------------- cast f32 -> bf16 ----------------
__global__ void cast_k(const float* __restrict__ in, ushort* __restrict__ out, int n) {
  int i = (blockIdx.x * blockDim.x + threadIdx.x) * 4;
  const int stride = gridDim.x * blockDim.x * 4;
  for (; i < n; i += stride) {
    float4 v = *reinterpret_cast<const float4*>(in + i);
    ushort4 o;
    o.x = f2b(v.x); o.y = f2b(v.y); o.z = f2b(v.z); o.w = f2b(v.w);
    *reinterpret_cast<ushort4*>(out + i) = o;
  }
}

__global__ void cast_w(const float* __restrict__ wq, const float* __restrict__ wk,
                       const float* __restrict__ wv, const float* __restrict__ wo,
                       ushort* __restrict__ wcat, ushort* __restrict__ wob) {
  const int i = (blockIdx.x * 256 + threadIdx.x) * 4;
  const int which = i >> 20, off = i & 1048575;
  const float* src = (which == 0) ? wq : (which == 1) ? wk : (which == 2) ? wv : wo;
  float4 v = *reinterpret_cast<const float4*>(src + off);
  ushort4 o;
  o.x = f2b(v.x); o.y = f2b(v.y); o.z = f2b(v.z); o.w = f2b(v.w);
  if (which < 3) *reinterpret_cast<ushort4*>(wcat + i) = o;
  else           *reinterpret_cast<ushort4*>(wob + off) = o;
}

// relvT[h][d] = relT[d][h] * log2(e)   (d = 0..4094)
__global__ void prep_rel(const float* __restrict__ relT, float* __restrict__ relvT) {
  const int t = blockIdx.x * 256 + threadIdx.x;
  if (t >= 16 * 4095) return;
  const int h = t / 4095, d = t - h * 4095;
  relvT[t] = relT[(size_t)d * 16 + h] * 1.4426950408889634f;
}

// ---------------- GEMM: C[M,N] = A[M,K] @ B[N,K]^T (+bias) ----------------
template <int MODE>
__global__ __launch_bounds__(256, 2)
void gemm_bt(const ushort* __restrict__ A, const ushort* __restrict__ B,
             const float* __restrict__ b0, const float* __restrict__ b1,
             const float* __restrict__ b2,
             float* __restrict__ outF, ushort* __restrict__ Qg,
             ushort* __restrict__ Kg, ushort* __restrict__ VTg, int N) {
  __shared__ __align__(16) ushort As[128][32];
  __shared__ __align__(16) ushort Bs[128][32];
  const int tid = threadIdx.x;
  const int m0 = blockIdx.y * 128, n0 = blockIdx.x * 128;
  const int wid = tid >> 6, lane = tid & 63, g = lane >> 4, li = lane & 15;
  const int wr = (wid >> 1) * 64, wc = (wid & 1) * 64;
  const int srow = lane >> 2, scol = (lane & 3) * 8;
  const ushort* gA0 = A + (size_t)(m0 + wid * 32 + srow) * 1024 + scol;
  const ushort* gB0 = B + (size_t)(n0 + wid * 32 + srow) * 1024 + scol;
  ushort* lA0 = &As[wid * 32][0];
  ushort* lA1 = &As[wid * 32 + 16][0];
  ushort* lB0 = &Bs[wid * 32][0];
  ushort* lB1 = &Bs[wid * 32 + 16][0];
  f32x4 acc[4][4] = {};
  for (int k0 = 0; k0 < 1024; k0 += 32) {
    __builtin_amdgcn_global_load_lds((const __attribute__((address_space(1))) void*)(gA0 + k0),
                                     (__attribute__((address_space(3))) void*)lA0, 16, 0, 0);
    __builtin_amdgcn_global_load_lds((const __attribute__((address_space(1))) void*)(gA0 + 16 * 1024 + k0),
                                     (__attribute__((address_space(3))) void*)lA1, 16, 0, 0);
    __builtin_amdgcn_global_load_lds((const __attribute__((address_space(1))) void*)(gB0 + k0),
                                     (__attribute__((address_space(3))) void*)lB0, 16, 0, 0);
    __builtin_amdgcn_global_load_lds((const __attribute__((address_space(1))) void*)(gB0 + 16 * 1024 + k0),
                                     (__attribute__((address_space(3))) void*)lB1, 16, 0, 0);
    __syncthreads();
    bf16x8 af[4], bfm[4];
#pragma unroll
    for (int i = 0; i < 4; ++i) {
      af[i]  = *reinterpret_cast<const bf16x8*>(&As[wr + i * 16 + li][g * 8]);
      bfm[i] = *reinterpret_cast<const bf16x8*>(&Bs[wc + i * 16 + li][g * 8]);
    }
#pragma unroll
    for (int mi = 0; mi < 4; ++mi)
#pragma unroll
      for (int ni = 0; ni < 4; ++ni)
        acc[mi][ni] = MFMA16(af[mi], bfm[ni], acc[mi][ni]);
    __syncthreads();
  }
#pragma unroll
  for (int mi = 0; mi < 4; ++mi) {
#pragma unroll
    for (int ni = 0; ni < 4; ++ni) {
      const int col = n0 + wc + ni * 16 + li;
#pragma unroll
      for (int r = 0; r < 4; ++r) {
        const int row = m0 + wr + mi * 16 + 4 * g + r;
        float v = acc[mi][ni][r];
        if (MODE == 0) {
          outF[(size_t)row * N + col] = v + b0[col];
        } else {
          const int which = col >> 10, c = col & 1023;
          const int hh = c >> 6, dk = c & 63;
          const int bb = row >> 11, t = row & 2047;
          const float* bias = (which == 0) ? b0 : ((which == 1) ? b1 : b2);
          const ushort bv = f2b(v + bias[c]);
          const size_t bhi = (size_t)(bb * 16 + hh);
          if (which == 0)      Qg[(bhi * 2048 + t) * 64 + dk] = bv;
          else if (which == 1) Kg[(bhi * 2048 + t) * 64 + dk] = bv;
          else                 VTg[(bhi * 64 + dk) * 2048 + t] = bv;
        }
      }
    }
  }
}

// ---------------- flash attention: fixed-max, split-k x4, permlane exchange ----
// grid: 2048 blocks = (bh, qt); block = 4 waves = 4 k-splits of one 32-row q-tile.
__global__ __launch_bounds__(256, 2)
void attn_k(const ushort* __restrict__ Qg, const ushort* __restrict__ Kg,
            const ushort* __restrict__ VTg, const float* __restrict__ relvT,
            ushort* __restrict__ Oa) {
  __shared__ float relv[2048];
  __shared__ float Obuf[3][64][33];
  __shared__ float lbuf[3][64];
  const int f = blockIdx.x;
  const int bh = (f & 7) * 4 + (f >> 9);      // same bh -> same XCD
  const int qt = (f >> 3) & 63;
  const int h = bh & 15, bb = bh >> 4;
  {
    const float* src = relvT + h * 4095 + 2047;
    for (int i = threadIdx.x; i < 2048; i += 256) relv[i] = src[i];
  }
  __syncthreads();
  const int wid = threadIdx.x >> 6, lane = threadIdx.x & 63;
  const int li = lane & 31, hi = lane >> 5;
  const int qb = qt * 32, q = qb + li;
  const ushort* Qb = Qg + (size_t)bh * (2048 * 64);
  const ushort* Kb = Kg + (size_t)bh * (2048 * 64);
  const ushort* Vb = VTg + (size_t)bh * (64 * 2048);
  bf16x8 qf[4];
#pragma unroll
  for (int c = 0; c < 4; ++c)
    qf[c] = *reinterpret_cast<const bf16x8*>(Qb + (size_t)q * 64 + c * 16 + hi * 8);
  f32x16 O[2] = {};
  float lacc[4] = {0.f, 0.f, 0.f, 0.f};
  const int nkt = (qt >> 1) + 1;
  const int nt = (wid < nkt) ? ((nkt - 1 - wid) >> 2) + 1 : 0;
  const int mask_kb = (nkt - 1) * 64;
  const float C1 = 0.18033688f;               // 0.125 * log2(e)
  if (nt > 0) {
    int kb = wid * 64;
    const int kb_last = kb + (nt - 1) * 256;
    bf16x8 Kr[8], Vr[8];
#pragma unroll
    for (int b = 0; b < 2; ++b)
#pragma unroll
      for (int c = 0; c < 4; ++c)
        Kr[b * 4 + c] = *reinterpret_cast<const bf16x8*>(Kb + (size_t)(kb + b * 32 + li) * 64 + c * 16 + hi * 8);
#pragma unroll
    for (int db = 0; db < 2; ++db)
#pragma unroll
      for (int c = 0; c < 4; ++c)
        Vr[db * 4 + c] = *reinterpret_cast<const bf16x8*>(Vb + (size_t)(db * 32 + li) * 2048 + kb + c * 16 + hi * 8);
    for (int i = 0; i < nt; ++i) {
      const int kbn = (i == nt - 1) ? kb_last : kb + 256;
      f32x16 S0 = {}, S1 = {};
#pragma unroll
      for (int c = 0; c < 4; ++c) S0 = MFMA32(Kr[c], qf[c], S0);
#pragma unroll
      for (int c = 0; c < 4; ++c) S1 = MFMA32(Kr[4 + c], qf[c], S1);
      // prefetch next K (WAR on Kr: issued after QK reads, lands during softmax)
#pragma unroll
      for (int b = 0; b < 2; ++b)
#pragma unroll
        for (int c = 0; c < 4; ++c)
          Kr[b * 4 + c] = *reinterpret_cast<const bf16x8*>(Kb + (size_t)(kbn + b * 32 + li) * 64 + c * 16 + hi * 8);
      const int dqb = q - kb - 4 * hi;
      const float* rl = relv + (dqb - 63);
      if (kb != mask_kb) {
#pragma unroll
        for (int r = 0; r < 16; ++r) {
          const int off0 = (r & 3) + 8 * (r >> 2);
          const float p0 = __builtin_amdgcn_exp2f(fmaf(S0[r], C1, rl[63 - off0]));
          const float p1 = __builtin_amdgcn_exp2f(fmaf(S1[r], C1, rl[31 - off0]));
          S0[r] = p0; S1[r] = p1;
          lacc[r & 3] += p0 + p1;
        }
      } else {
#pragma unroll
        for (int r = 0; r < 16; ++r) {
          const int off0 = (r & 3) + 8 * (r >> 2);
          const int d0 = dqb - off0, d1 = d0 - 32;
          float p0 = __builtin_amdgcn_exp2f(fmaf(S0[r], C1, relv[d0 & 2047]));
          float p1 = __builtin_amdgcn_exp2f(fmaf(S1[r], C1, relv[d1 & 2047]));
          p0 = (d0 >= 0) ? p0 : 0.f;
          p1 = (d1 >= 0) ? p1 : 0.f;
          S0[r] = p0; S1[r] = p1;
          lacc[r & 3] += p0 + p1;
        }
      }
      unsigned U0[4][2], U1[4][2];
#pragma unroll
      for (int rg = 0; rg < 4; ++rg) {
        U0[rg][0] = cvtpk(S0[4 * rg + 0], S0[4 * rg + 1]);
        U0[rg][1] = cvtpk(S0[4 * rg + 2], S0[4 * rg + 3]);
        U1[rg][0] = cvtpk(S1[4 * rg + 0], S1[4 * rg + 1]);
        U1[rg][1] = cvtpk(S1[4 * rg + 2], S1[4 * rg + 3]);
      }
#pragma unroll
      for (int c = 0; c < 4; ++c) {
        const int c0 = c & 1;
        unsigned x0 = (c < 2) ? U0[2 * c0][0] : U1[2 * c0][0];
        unsigned y0 = (c < 2) ? U0[2 * c0 + 1][0] : U1[2 * c0 + 1][0];
        unsigned x1 = (c < 2) ? U0[2 * c0][1] : U1[2 * c0][1];
        unsigned y1 = (c < 2) ? U0[2 * c0 + 1][1] : U1[2 * c0 + 1][1];
        plswap(x0, y0);
        plswap(x1, y1);
        union { unsigned u[4]; bf16x8 v; } P;
        P.u[0] = x0; P.u[1] = x1; P.u[2] = y0; P.u[3] = y1;
#pragma unroll
        for (int db = 0; db < 2; ++db)
          O[db] = MFMA32(Vr[db * 4 + c], P.v, O[db]);
      }
      // prefetch next V
#pragma unroll
      for (int db = 0; db < 2; ++db)
#pragma unroll
        for (int c = 0; c < 4; ++c)
          Vr[db * 4 + c] = *reinterpret_cast<const bf16x8*>(Vb + (size_t)(db * 32 + li) * 2048 + kbn + c * 16 + hi * 8);
      kb = kbn;
    }
  }
  // -------- merge (pure sums: no max tracking) --------
  __syncthreads();
  if (wid) {
    float* ob = &Obuf[wid - 1][lane][0];
#pragma unroll
    for (int db = 0; db < 2; ++db)
#pragma unroll
      for (int r = 0; r < 16; ++r)
        ob[db * 16 + r] = O[db][r];
    lbuf[wid - 1][lane] = lacc[0] + lacc[1] + lacc[2] + lacc[3];
  }
  __syncthreads();
  if (wid == 0) {
    float lh = lacc[0] + lacc[1] + lacc[2] + lacc[3];
#pragma unroll
    for (int w = 0; w < 3; ++w) {
      lh += lbuf[w][lane];
      const float* ob = &Obuf[w][lane][0];
#pragma unroll
      for (int db = 0; db < 2; ++db)
#pragma unroll
        for (int r = 0; r < 16; ++r)
          O[db][r] += ob[db * 16 + r];
    }
    unsigned xa = __float_as_uint(lh), xb2 = xa;
    plswap(xa, xb2);                      // xa = [lo|lo], xb2 = [hi|hi]
    const float linv = 1.f / (__uint_as_float(xa) + __uint_as_float(xb2));
    ushort* orow = Oa + ((size_t)(bb * 2048 + q)) * 1024 + h * 64;
#pragma unroll
    for (int db = 0; db < 2; ++db)
#pragma unroll
      for (int rg = 0; rg < 4; ++rg) {
        ushort4 o;
        o.x = f2b(O[db][4 * rg + 0] * linv);
        o.y = f2b(O[db][4 * rg + 1] * linv);
        o.z = f2b(O[db][4 * rg + 2] * linv);
        o.w = f2b(O[db][4 * rg + 3] * linv);
        *reinterpret_cast<ushort4*>(orow + db * 32 + 8 * rg + 4 * hi) = o;
      }
  }
}

extern "C" void kernel_launch(void* const* d_in, const int* in_sizes, int n_in,
                              void* d_out, int out_size, void* d_ws, size_t ws_size,
                              hipStream_t stream) {
  const float* x    = (const float*)d_in[0];
  const float* WQ   = (const float*)d_in[1];
  const float* bQ   = (const float*)d_in[2];
  const float* WK   = (const float*)d_in[3];
  const float* bK   = (const float*)d_in[4];
  const float* WV   = (const float*)d_in[5];
  const float* bV   = (const float*)d_in[6];
  const float* WO   = (const float*)d_in[7];
  const float* bO   = (const float*)d_in[8];
  const float* relT = (const float*)d_in[9];
  float* out = (float*)d_out;

  if (ws_size < (size_t)48 * 1024 * 1024) return;

  char* ws = (char*)d_ws;
  ushort* xb    = (ushort*)(ws);                    // [4096][1024] bf16 (dead after gemm1)
  float*  relvT = (float*)(ws);                     // [16][4095] f32 — overlays xb after gemm1
  ushort* Wcat  = (ushort*)(ws + 8 * 1024 * 1024);  // [3072][1024] bf16
  ushort* WOb   = (ushort*)(ws + 14 * 1024 * 1024); // [1024][1024] bf16
  ushort* Qg    = (ushort*)(ws + 16 * 1024 * 1024); // [2,16,2048,64] bf16
  ushort* Kg    = (ushort*)(ws + 24 * 1024 * 1024); // [2,16,2048,64] bf16
  ushort* VTg   = (ushort*)(ws + 32 * 1024 * 1024); // [2,16,64,2048] bf16
  ushort* Oa    = (ushort*)(ws + 40 * 1024 * 1024); // [4096][1024] bf16

  cast_k<<<1024, 256, 0, stream>>>(x, xb, 4096 * 1024);
  cast_w<<<4096, 256, 0, stream>>>(WQ, WK, WV, WO, Wcat, WOb);

  gemm_bt<1><<<dim3(24, 32), 256, 0, stream>>>(xb, Wcat, bQ, bK, bV,
                                               nullptr, Qg, Kg, VTg, 3072);
  prep_rel<<<256, 256, 0, stream>>>(relT, relvT);   // after gemm1: overlays xb
  attn_k<<<2048, 256, 0, stream>>>(Qg, Kg, VTg, relvT, Oa);
  gemm_bt<0><<<dim3(8, 32), 256, 0, stream>>>(Oa, WOb, bO, nullptr, nullptr,
                                              out, nullptr, nullptr, nullptr, 1024);
}